// Round 4
// baseline (2774.102 us; speedup 1.0000x reference)
//
#include <hip/hip_runtime.h>

// CrossAttention: x_qkv->K,V ; y_q->Q ; CLS full attn + patch 3x3 local attn ; @Wo+bo
// I/O is float32 (per reference dtypes). Internals: bf16 MFMA GEMMs (weights
// pre-converted, A-tiles converted during LDS staging), fp32 everywhere else.
// Batch processed in 16 chunks of 8 images -> ~19 MB of d_ws.

typedef __bf16 bf16x8 __attribute__((ext_vector_type(8)));
typedef float f32x4 __attribute__((ext_vector_type(4)));

#define NTOK 197
#define CHUNK_B 8
#define NCHUNK 16
#define MC (CHUNK_B * NTOK)          // 1576 rows per chunk
#define MTILES 13                    // ceil(1576/128)
#define W_ELEMS ((size_t)768 * 768)
#define BUF_ELEMS ((size_t)MC * 768) // 1,210,368 elems per chunk buffer

__device__ __forceinline__ unsigned short f2b(float f) {
  unsigned int x = __float_as_uint(f);
  x += 0x7fff + ((x >> 16) & 1);          // RNE
  return (unsigned short)(x >> 16);
}

// -------- weight transpose+convert: Wt[n*768+k] = bf16(W[k*768+n]) --------
__global__ void transpose768(const float* __restrict__ src,
                             unsigned short* __restrict__ dst) {
  int idx = blockIdx.x * 256 + threadIdx.x;   // 589824 total
  int n = idx / 768, k = idx % 768;
  dst[idx] = f2b(src[k * 768 + n]);
}

// -------- bf16 MFMA GEMM: C[MC,768] = A[MC,768] @ Wt^T + bias (fp32 io) ----
// A fp32 (converted to bf16 in staging), Wt bf16 N-major, C fp32.
// 128x128 block tile, BK=32, 4 waves (2x2), wave = 4x4 MFMA 16x16x32 tiles.
__global__ __launch_bounds__(256, 2) void gemm_bt(
    const float* __restrict__ A, const unsigned short* __restrict__ Wt,
    const float* __restrict__ bias, float* __restrict__ C) {
  __shared__ unsigned short sAB[8192];   // As[128][32] | Bs[128][32] (bf16)
  const int tid = threadIdx.x;
  const int l = tid & 63, w = tid >> 6;
  const int wr = w >> 1, wc = w & 1;
  const int lane16 = l & 15, quad = l >> 4;
  const int row0 = blockIdx.y * 128;
  const int n0 = blockIdx.x * 128;

  f32x4 acc[4][4] = {};

  for (int kt = 0; kt < 24; ++kt) {
    const int k0 = kt * 32;
    // stage: 512 chunks of 8 elems for A (fp32->bf16) and B (bf16 copy)
    #pragma unroll
    for (int i = 0; i < 2; ++i) {
      const int ch = i * 256 + tid;          // 0..511
      const int rr = ch >> 2;                // tile row
      const int c8 = (ch & 3) * 8;           // elem offset within 32-wide k
      int ra = row0 + rr; if (ra > MC - 1) ra = MC - 1;   // M edge clamp
      const float* ap = A + (size_t)ra * 768 + k0 + c8;
      float4 f0 = *(const float4*)ap;
      float4 f1 = *(const float4*)(ap + 4);
      unsigned short t8[8] = { f2b(f0.x), f2b(f0.y), f2b(f0.z), f2b(f0.w),
                               f2b(f1.x), f2b(f1.y), f2b(f1.z), f2b(f1.w) };
      *(uint4*)&sAB[rr * 32 + c8] = *(const uint4*)t8;
      uint4 vb = *(const uint4*)(Wt + (size_t)(n0 + rr) * 768 + k0 + c8);
      *(uint4*)&sAB[4096 + rr * 32 + c8] = vb;
    }
    __syncthreads();
    bf16x8 af[4], bfr[4];
    #pragma unroll
    for (int i = 0; i < 4; ++i)
      af[i] = *(const bf16x8*)&sAB[(wr * 64 + i * 16 + lane16) * 32 + quad * 8];
    #pragma unroll
    for (int j = 0; j < 4; ++j)
      bfr[j] = *(const bf16x8*)&sAB[4096 + (wc * 64 + j * 16 + lane16) * 32 + quad * 8];
    #pragma unroll
    for (int i = 0; i < 4; ++i)
      #pragma unroll
      for (int j = 0; j < 4; ++j)
        acc[i][j] = __builtin_amdgcn_mfma_f32_16x16x32_bf16(af[i], bfr[j], acc[i][j], 0, 0, 0);
    __syncthreads();
  }

  #pragma unroll
  for (int j = 0; j < 4; ++j) {
    const int col = n0 + wc * 64 + j * 16 + lane16;
    const float bv = bias[col];
    #pragma unroll
    for (int i = 0; i < 4; ++i) {
      const int r0 = row0 + wr * 64 + i * 16 + quad * 4;
      #pragma unroll
      for (int r = 0; r < 4; ++r)
        if (r0 + r < MC)
          C[(size_t)(r0 + r) * 768 + col] = acc[i][j][r] + bv;
    }
  }
}

// -------- CLS token: full attention over 197 keys. 1 block per (b,h) --------
__global__ void cls_attn(const float* __restrict__ Q,
                         const float* __restrict__ K,
                         const float* __restrict__ V,
                         float* __restrict__ ATT) {
  __shared__ float q[64];
  __shared__ float attn[256];
  __shared__ float red[8];
  const int tid = threadIdx.x, l = tid & 63, w = tid >> 6;
  const int b = blockIdx.x / 12, h = blockIdx.x % 12;
  const size_t rowbase = ((size_t)b * NTOK) * 768 + h * 64;

  if (tid < 64) q[tid] = Q[rowbase + tid];
  __syncthreads();

  float d = -3e38f;
  if (tid < NTOK) {
    const float4* Kp = (const float4*)(K + rowbase + (size_t)tid * 768);
    float s = 0.f;
    #pragma unroll
    for (int u = 0; u < 16; ++u) {
      float4 kk = Kp[u];
      s += q[u * 4 + 0] * kk.x + q[u * 4 + 1] * kk.y
         + q[u * 4 + 2] * kk.z + q[u * 4 + 3] * kk.w;
    }
    d = s * 0.125f;
  }
  float m = d;
  #pragma unroll
  for (int off = 32; off; off >>= 1) m = fmaxf(m, __shfl_xor(m, off, 64));
  if (l == 0) red[w] = m;
  __syncthreads();
  const float M = fmaxf(fmaxf(red[0], red[1]), fmaxf(red[2], red[3]));
  float e = (tid < NTOK) ? __expf(d - M) : 0.f;
  float ssum = e;
  #pragma unroll
  for (int off = 32; off; off >>= 1) ssum += __shfl_xor(ssum, off, 64);
  if (l == 0) red[4 + w] = ssum;
  __syncthreads();
  const float S = red[4] + red[5] + red[6] + red[7];
  attn[tid] = e / S;
  __syncthreads();
  if (tid < 64) {
    float o = 0.f;
    for (int j = 0; j < NTOK; ++j)
      o += attn[j] * V[rowbase + (size_t)j * 768 + tid];
    ATT[rowbase + tid] = o;
  }
}

// -------- patch tokens: 3x3 local attention. 1 wave per (b,p,h) --------
__global__ void patch_attn(const float* __restrict__ Q,
                           const float* __restrict__ K,
                           const float* __restrict__ V,
                           float* __restrict__ ATT) {
  const int wgid = blockIdx.x * 4 + (threadIdx.x >> 6);
  const int l = threadIdx.x & 63;
  const int h = wgid % 12;
  const int t2 = wgid / 12;
  const int p = t2 % 196;
  const int b = t2 / 196;
  const int r = p / 14, c = p % 14;
  const size_t base = ((size_t)b * NTOK) * 768 + h * 64 + l;

  const float qd = Q[base + (size_t)(p + 1) * 768];

  float s[9];
  int tok[9];
  #pragma unroll
  for (int jj = 0; jj < 9; ++jj) {
    const int nr = r + jj / 3 - 1, nc = c + jj % 3 - 1;
    const bool ok = ((unsigned)nr < 14u) && ((unsigned)nc < 14u);
    tok[jj] = ok ? (1 + nr * 14 + nc) : (p + 1);
    float d = qd * K[base + (size_t)tok[jj] * 768];
    #pragma unroll
    for (int off = 32; off; off >>= 1) d += __shfl_xor(d, off, 64);
    s[jj] = ok ? d * 0.125f : -3e38f;
  }
  float m = s[0];
  #pragma unroll
  for (int jj = 1; jj < 9; ++jj) m = fmaxf(m, s[jj]);
  float sum = 0.f;
  #pragma unroll
  for (int jj = 0; jj < 9; ++jj) { s[jj] = __expf(s[jj] - m); sum += s[jj]; }
  const float inv = 1.f / sum;
  float o = 0.f;
  #pragma unroll
  for (int jj = 0; jj < 9; ++jj) o += s[jj] * V[base + (size_t)tok[jj] * 768];
  ATT[base + (size_t)(p + 1) * 768] = o * inv;
}

extern "C" void kernel_launch(void* const* d_in, const int* in_sizes, int n_in,
                              void* d_out, int out_size, void* d_ws, size_t ws_size,
                              hipStream_t stream) {
  const float* x  = (const float*)d_in[0];
  const float* y  = (const float*)d_in[1];
  const float* Wq = (const float*)d_in[2];
  const float* bq = (const float*)d_in[3];
  const float* Wk = (const float*)d_in[4];
  const float* bk = (const float*)d_in[5];
  const float* Wv = (const float*)d_in[6];
  const float* bv = (const float*)d_in[7];
  const float* Wo = (const float*)d_in[8];
  const float* bo = (const float*)d_in[9];
  float* out = (float*)d_out;

  // ws layout (~19.2 MB): 4 bf16 transposed weights, then fp32 K,V,Q chunk bufs
  unsigned short* WqT = (unsigned short*)d_ws;
  unsigned short* WkT = WqT + W_ELEMS;
  unsigned short* WvT = WkT + W_ELEMS;
  unsigned short* WoT = WvT + W_ELEMS;
  float* Kc = (float*)(WoT + W_ELEMS);
  float* Vc = Kc + BUF_ELEMS;
  float* Qc = Vc + BUF_ELEMS;   // attention output aliases Qc

  transpose768<<<2304, 256, 0, stream>>>(Wq, WqT);
  transpose768<<<2304, 256, 0, stream>>>(Wk, WkT);
  transpose768<<<2304, 256, 0, stream>>>(Wv, WvT);
  transpose768<<<2304, 256, 0, stream>>>(Wo, WoT);

  dim3 ggrid(6, MTILES);   // N tiles x M tiles
  for (int c = 0; c < NCHUNK; ++c) {
    const float* xc = x + (size_t)c * BUF_ELEMS;
    const float* yc = y + (size_t)c * BUF_ELEMS;
    gemm_bt<<<ggrid, 256, 0, stream>>>(xc, WkT, bk, Kc);
    gemm_bt<<<ggrid, 256, 0, stream>>>(xc, WvT, bv, Vc);
    gemm_bt<<<ggrid, 256, 0, stream>>>(yc, WqT, bq, Qc);
    cls_attn<<<CHUNK_B * 12, 256, 0, stream>>>(Qc, Kc, Vc, Qc);
    patch_attn<<<(CHUNK_B * 196 * 12) / 4, 256, 0, stream>>>(Qc, Kc, Vc, Qc);
    gemm_bt<<<ggrid, 256, 0, stream>>>(Qc, WoT, bo, out + (size_t)c * BUF_ELEMS);
  }
}